// Round 1
// baseline (163.429 us; speedup 1.0000x reference)
//
#include <hip/hip_runtime.h>

#define NPTS   6144
#define DIM    32
#define NBATCH 2
#define TILE   1024
#define NWAVES 4
#define BLOCK  (NWAVES * 64)

// One wave per point i; 4 waves (4 points) per block share LDS-staged tiles of
// (points, leaf). Radius hits are ~0.4% of pairs -> similarity dot is a rare
// divergent branch; sim>0.7 survivors (~self only) accumulate via LDS atomics.
__global__ __launch_bounds__(BLOCK)
void leaf_refine(const float* __restrict__ points,
                 const float* __restrict__ emb,
                 const int*   __restrict__ leaf,
                 const float* __restrict__ W1,
                 const float* __restrict__ b1,
                 const float* __restrict__ W2,
                 const float* __restrict__ b2,
                 float* __restrict__ out)
{
    __shared__ float s_px[TILE];
    __shared__ float s_py[TILE];
    __shared__ float s_pz[TILE];
    __shared__ int   s_leaf[TILE];
    __shared__ __align__(16) float s_ei[NWAVES][DIM];
    __shared__ float s_ssum[NWAVES][DIM];
    __shared__ float s_h[NWAVES][DIM];
    __shared__ int   s_csim[NWAVES];

    const int tid  = threadIdx.x;
    const int wid  = tid >> 6;
    const int lane = tid & 63;
    const int pt   = blockIdx.x * NWAVES + wid;   // [0, NBATCH*NPTS)
    const int b    = pt / NPTS;
    const int i    = pt - b * NPTS;

    const float* embB  = emb    + (size_t)b * NPTS * DIM;
    const int*   leafB = leaf   + (size_t)b * NPTS;
    const float* ptsB  = points + (size_t)b * NPTS * 3;

    if (lane < DIM) {
        s_ei[wid][lane]   = embB[(size_t)i * DIM + lane];
        s_ssum[wid][lane] = 0.0f;
    }
    if (lane == 0) s_csim[wid] = 0;

    // ||e_i|| (wave-uniform; LDS broadcast reads)
    float ni2 = 0.0f;
    #pragma unroll
    for (int d = 0; d < DIM; ++d) { float v = s_ei[wid][d]; ni2 += v * v; }
    const float rni = 1.0f / fmaxf(sqrtf(ni2), 1e-8f);

    const float pix = ptsB[(size_t)i * 3 + 0];
    const float piy = ptsB[(size_t)i * 3 + 1];
    const float piz = ptsB[(size_t)i * 3 + 2];

    const float R2 = (float)(0.03 * 0.03);

    int cnt_nb  = 0;  // includes self when leaf[i] (matches reference)
    int leafcnt = 0;  // sum(leaf_mask) for this batch (values are 0/1)

    for (int t0 = 0; t0 < NPTS; t0 += TILE) {
        __syncthreads();
        for (int k = tid; k < TILE; k += BLOCK) {
            const int j = t0 + k;
            s_px[k]   = ptsB[(size_t)j * 3 + 0];
            s_py[k]   = ptsB[(size_t)j * 3 + 1];
            s_pz[k]   = ptsB[(size_t)j * 3 + 2];
            s_leaf[k] = leafB[j];
        }
        __syncthreads();

        for (int c = 0; c < TILE; c += 64) {
            const int   k  = c + lane;
            const float dx = s_px[k] - pix;
            const float dy = s_py[k] - piy;
            const float dz = s_pz[k] - piz;
            const float d2 = dx * dx + dy * dy + dz * dz;
            const int   lj = s_leaf[k];
            const bool  isleaf = lj > 0;
            const bool  nb = (d2 < R2) && isleaf;

            leafcnt += __popcll(__ballot(isleaf));
            const unsigned long long mnb = __ballot(nb);
            cnt_nb += __popcll(mnb);

            if (mnb) {                    // wave-uniform skip of empty chunks
                if (nb) {                 // divergent: ~0.27 lanes/chunk
                    const float* ej = embB + (size_t)(t0 + k) * DIM;
                    float dot = 0.0f, nj2 = 0.0f;
                    #pragma unroll
                    for (int d0 = 0; d0 < DIM; d0 += 4) {
                        const float4 a  = *(const float4*)&s_ei[wid][d0];
                        const float4 bj = *(const float4*)&ej[d0];
                        dot += a.x * bj.x + a.y * bj.y + a.z * bj.z + a.w * bj.w;
                        nj2 += bj.x * bj.x + bj.y * bj.y + bj.z * bj.z + bj.w * bj.w;
                    }
                    const float rnj = 1.0f / fmaxf(sqrtf(nj2), 1e-8f);
                    const float sim = dot * rni * rnj;
                    if (sim > 0.7f) {     // ~1 survivor per point (self)
                        atomicAdd(&s_csim[wid], 1);
                        #pragma unroll
                        for (int d = 0; d < DIM; ++d)
                            atomicAdd(&s_ssum[wid][d], ej[d]);
                    }
                }
            }
        }
    }

    const int  csim = s_csim[wid];
    const bool ok   = (leafcnt >= 10);
    const bool li   = leafB[i] > 0;
    const bool cond = ok && li && (cnt_nb > 1) && (csim > 0);  // wave-uniform

    float* outp = out + ((size_t)b * NPTS + i) * DIM;
    if (lane < DIM) {
        if (!cond) {
            outp[lane] = s_ei[wid][lane];
        } else {
            // mean of similar-neighbor embeddings
            s_ssum[wid][lane] = s_ssum[wid][lane] / (float)csim;
            // h = relu([e_i, mean] @ W1 + b1); W1 is [2D][D] row-major
            float acc = b1[lane];
            for (int k = 0; k < DIM; ++k)
                acc = fmaf(s_ei[wid][k],   W1[k * DIM + lane], acc);
            for (int k = 0; k < DIM; ++k)
                acc = fmaf(s_ssum[wid][k], W1[(DIM + k) * DIM + lane], acc);
            s_h[wid][lane] = fmaxf(acc, 0.0f);
            // out = h @ W2 + b2
            float acc2 = b2[lane];
            for (int k = 0; k < DIM; ++k)
                acc2 = fmaf(s_h[wid][k], W2[k * DIM + lane], acc2);
            outp[lane] = acc2;
        }
    }
}

extern "C" void kernel_launch(void* const* d_in, const int* in_sizes, int n_in,
                              void* d_out, int out_size, void* d_ws, size_t ws_size,
                              hipStream_t stream) {
    const float* points = (const float*)d_in[0];
    const float* emb    = (const float*)d_in[1];
    const int*   leaf   = (const int*)d_in[2];
    const float* W1     = (const float*)d_in[3];
    const float* b1     = (const float*)d_in[4];
    const float* W2     = (const float*)d_in[5];
    const float* b2     = (const float*)d_in[6];
    float*       outp   = (float*)d_out;

    const int grid = (NBATCH * NPTS) / NWAVES;   // 3072 blocks
    leaf_refine<<<grid, BLOCK, 0, stream>>>(points, emb, leaf, W1, b1, W2, b2, outp);
}